// Round 1
// baseline (275.232 us; speedup 1.0000x reference)
//
#include <hip/hip_runtime.h>

// Problem constants (from reference): B=32, C=768, H=W=24 -> HW=576
#define B_  32
#define C_  768
#define HW_ 576

typedef __bf16 bf16x8 __attribute__((ext_vector_type(8)));
typedef float  f32x4  __attribute__((ext_vector_type(4)));

__device__ __forceinline__ unsigned short f2bf(float x) {
    unsigned u = __builtin_bit_cast(unsigned, x);
    u += 0x7FFFu + ((u >> 16) & 1u);   // round-to-nearest-even
    return (unsigned short)(u >> 16);
}
__device__ __forceinline__ float bf2f(unsigned short h) {
    unsigned u = ((unsigned)h) << 16;
    return __builtin_bit_cast(float, u);
}

// ---------------------------------------------------------------------------
// Kernel 1: attn[bz][c][d] = sum_n q[b][c][n] * kv[b][d][n]
// NT GEMM: both operands row-major, K (=n, HW) contiguous.
// bf16 hi/lo split for ~fp32 accuracy: acc += hh + hl + lh.
// Tile 128x128, BK=32, 4 waves each 64x64 (4x4 frags of 16x16x32).
// ---------------------------------------------------------------------------
__global__ __launch_bounds__(256) void qk_kernel(const float* __restrict__ q,
                                                 const float* __restrict__ kv,
                                                 float* __restrict__ attn,
                                                 int b0) {
    __shared__ unsigned short Ahi[128][40];
    __shared__ unsigned short Alo[128][40];
    __shared__ unsigned short Bhi[128][40];
    __shared__ unsigned short Blo[128][40];

    const int ti = blockIdx.x;            // attn row tile (c)
    const int tj = blockIdx.y;            // attn col tile (d)
    const int b  = b0 + blockIdx.z;

    const float* qb = q  + (size_t)b * C_ * HW_ + (size_t)ti * 128 * HW_;
    const float* kb = kv + (size_t)b * C_ * HW_ + (size_t)tj * 128 * HW_;

    const int t    = threadIdx.x;
    const int lane = t & 63;
    const int w    = t >> 6;
    const int wr   = (w >> 1) * 64;       // wave row offset in tile
    const int wc   = (w & 1)  * 64;       // wave col offset in tile

    f32x4 acc[4][4] = {};

    for (int k0 = 0; k0 < HW_; k0 += 32) {
        // --- stage A (q rows) and B (kv rows) as bf16 hi/lo ---
        #pragma unroll
        for (int u = 0; u < 4; ++u) {
            int idx = t + 256 * u;        // 0..1023 float4 slots (128 rows x 8)
            int row = idx >> 3;
            int c4  = idx & 7;
            f32x4 va = *reinterpret_cast<const f32x4*>(qb + (size_t)row * HW_ + k0 + c4 * 4);
            f32x4 vb = *reinterpret_cast<const f32x4*>(kb + (size_t)row * HW_ + k0 + c4 * 4);
            #pragma unroll
            for (int e = 0; e < 4; ++e) {
                unsigned short h = f2bf(va[e]);
                Ahi[row][c4 * 4 + e] = h;
                Alo[row][c4 * 4 + e] = f2bf(va[e] - bf2f(h));
                h = f2bf(vb[e]);
                Bhi[row][c4 * 4 + e] = h;
                Blo[row][c4 * 4 + e] = f2bf(vb[e] - bf2f(h));
            }
        }
        __syncthreads();

        const int r  = lane & 15;
        const int ko = (lane >> 4) * 8;
        bf16x8 ah[4], al[4], bh[4], bl[4];
        #pragma unroll
        for (int m = 0; m < 4; ++m) {
            ah[m] = *reinterpret_cast<const bf16x8*>(&Ahi[wr + m * 16 + r][ko]);
            al[m] = *reinterpret_cast<const bf16x8*>(&Alo[wr + m * 16 + r][ko]);
            bh[m] = *reinterpret_cast<const bf16x8*>(&Bhi[wc + m * 16 + r][ko]);
            bl[m] = *reinterpret_cast<const bf16x8*>(&Blo[wc + m * 16 + r][ko]);
        }
        #pragma unroll
        for (int m = 0; m < 4; ++m)
            #pragma unroll
            for (int n = 0; n < 4; ++n) {
                acc[m][n] = __builtin_amdgcn_mfma_f32_16x16x32_bf16(ah[m], bh[n], acc[m][n], 0, 0, 0);
                acc[m][n] = __builtin_amdgcn_mfma_f32_16x16x32_bf16(ah[m], bl[n], acc[m][n], 0, 0, 0);
                acc[m][n] = __builtin_amdgcn_mfma_f32_16x16x32_bf16(al[m], bh[n], acc[m][n], 0, 0, 0);
            }
        __syncthreads();
    }

    // write attn tile (chunk-local batch index!)
    float* ab = attn + ((size_t)blockIdx.z * C_ + ti * 128) * C_ + tj * 128;
    const int col   = lane & 15;
    const int rbase = (lane >> 4) * 4;
    #pragma unroll
    for (int m = 0; m < 4; ++m)
        #pragma unroll
        for (int n = 0; n < 4; ++n)
            #pragma unroll
            for (int rg = 0; rg < 4; ++rg)
                ab[(size_t)(wr + m * 16 + rbase + rg) * C_ + wc + n * 16 + col] = acc[m][n][rg];
}

// ---------------------------------------------------------------------------
// Kernel 2: row softmax over last dim (C_=768) of attn, in place, fp32.
// One wave per row; 4 rows per 256-thread block.
// ---------------------------------------------------------------------------
__global__ __launch_bounds__(256) void softmax_kernel(float* __restrict__ attn) {
    const int row  = blockIdx.x * 4 + (threadIdx.x >> 6);
    const int lane = threadIdx.x & 63;
    float* p = attn + (size_t)row * C_;

    f32x4 v[3];
    float mx = -1e30f;
    #pragma unroll
    for (int u = 0; u < 3; ++u) {
        v[u] = *reinterpret_cast<const f32x4*>(p + (size_t)(lane + 64 * u) * 4);
        #pragma unroll
        for (int e = 0; e < 4; ++e) mx = fmaxf(mx, v[u][e]);
    }
    #pragma unroll
    for (int o = 32; o > 0; o >>= 1) mx = fmaxf(mx, __shfl_xor(mx, o));

    float s = 0.f;
    #pragma unroll
    for (int u = 0; u < 3; ++u)
        #pragma unroll
        for (int e = 0; e < 4; ++e) {
            v[u][e] = __expf(v[u][e] - mx);
            s += v[u][e];
        }
    #pragma unroll
    for (int o = 32; o > 0; o >>= 1) s += __shfl_xor(s, o);
    const float inv = 1.0f / s;

    #pragma unroll
    for (int u = 0; u < 3; ++u) {
        f32x4 o4;
        #pragma unroll
        for (int e = 0; e < 4; ++e) o4[e] = v[u][e] * inv;
        *reinterpret_cast<f32x4*>(p + (size_t)(lane + 64 * u) * 4) = o4;
    }
}

// ---------------------------------------------------------------------------
// Kernel 3: info = P @ V, out = gamma*info + feat1.
// P: [C_][C_] fp32 (k contiguous -> A frags direct).
// V = kv: [C_(d)][HW_(n)] row-major -> staged TRANSPOSED to LDS [n][k].
// Tile 128x64, BK=32, 4 waves each 64x32 (4x2 frags). Plain bf16 (safe: P in [0,1]).
// ---------------------------------------------------------------------------
__global__ __launch_bounds__(256) void pv_kernel(const float* __restrict__ attn,
                                                 const float* __restrict__ kv,
                                                 const float* __restrict__ feat1,
                                                 const float* __restrict__ gamma,
                                                 float* __restrict__ out,
                                                 int b0) {
    __shared__ unsigned short As[128][40];
    __shared__ unsigned short Bs[64][40];

    const int ti = blockIdx.x;            // C tile (128)
    const int tj = blockIdx.y;            // HW tile (64)
    const int bz = blockIdx.z;
    const int b  = b0 + bz;

    const float* Pb = attn + (size_t)bz * C_ * C_ + (size_t)ti * 128 * C_;
    const float* Vb = kv   + (size_t)b * C_ * HW_;

    const int t    = threadIdx.x;
    const int lane = t & 63;
    const int w    = t >> 6;
    const int wr   = (w >> 1) * 64;
    const int wc   = (w & 1)  * 32;

    f32x4 acc[4][2] = {};

    for (int k0 = 0; k0 < C_; k0 += 32) {
        // stage A: P tile 128x32 fp32 -> bf16
        #pragma unroll
        for (int u = 0; u < 4; ++u) {
            int idx = t + 256 * u;
            int row = idx >> 3;
            int c4  = idx & 7;
            f32x4 va = *reinterpret_cast<const f32x4*>(Pb + (size_t)row * C_ + k0 + c4 * 4);
            #pragma unroll
            for (int e = 0; e < 4; ++e) As[row][c4 * 4 + e] = f2bf(va[e]);
        }
        // stage B: V tile 32(k) x 64(n), transposed into LDS [n][k]
        #pragma unroll
        for (int u = 0; u < 2; ++u) {
            int idx = t + 256 * u;        // 0..511 float4 slots (32 k x 16)
            int kk  = idx >> 4;
            int n4  = idx & 15;
            f32x4 vb = *reinterpret_cast<const f32x4*>(Vb + (size_t)(k0 + kk) * HW_ + tj * 64 + n4 * 4);
            #pragma unroll
            for (int e = 0; e < 4; ++e) Bs[n4 * 4 + e][kk] = f2bf(vb[e]);
        }
        __syncthreads();

        const int r  = lane & 15;
        const int ko = (lane >> 4) * 8;
        bf16x8 a[4], bb[2];
        #pragma unroll
        for (int m = 0; m < 4; ++m)
            a[m] = *reinterpret_cast<const bf16x8*>(&As[wr + m * 16 + r][ko]);
        #pragma unroll
        for (int n = 0; n < 2; ++n)
            bb[n] = *reinterpret_cast<const bf16x8*>(&Bs[wc + n * 16 + r][ko]);

        #pragma unroll
        for (int m = 0; m < 4; ++m)
            #pragma unroll
            for (int n = 0; n < 2; ++n)
                acc[m][n] = __builtin_amdgcn_mfma_f32_16x16x32_bf16(a[m], bb[n], acc[m][n], 0, 0, 0);
        __syncthreads();
    }

    const float g = gamma[0];
    const float* f1 = feat1 + (size_t)b * C_ * HW_ + (size_t)ti * 128 * HW_ + tj * 64;
    float*       ob = out   + (size_t)b * C_ * HW_ + (size_t)ti * 128 * HW_ + tj * 64;
    const int col   = lane & 15;
    const int rbase = (lane >> 4) * 4;
    #pragma unroll
    for (int m = 0; m < 4; ++m)
        #pragma unroll
        for (int n = 0; n < 2; ++n)
            #pragma unroll
            for (int rg = 0; rg < 4; ++rg) {
                int rr = wr + m * 16 + rbase + rg;
                int cc = wc + n * 16 + col;
                ob[(size_t)rr * HW_ + cc] = g * acc[m][n][rg] + f1[(size_t)rr * HW_ + cc];
            }
}

// ---------------------------------------------------------------------------
extern "C" void kernel_launch(void* const* d_in, const int* in_sizes, int n_in,
                              void* d_out, int out_size, void* d_ws, size_t ws_size,
                              hipStream_t stream) {
    const float* feat1 = (const float*)d_in[0];
    const float* feat2 = (const float*)d_in[1];
    const float* gamma = (const float*)d_in[2];
    float* out  = (float*)d_out;
    float* attn = (float*)d_ws;

    const size_t bytes_per_batch = (size_t)C_ * C_ * sizeof(float);  // 2.36 MB
    int nb = (int)(ws_size / bytes_per_batch);
    if (nb < 1) nb = 1;
    if (nb > B_) nb = B_;

    for (int b0 = 0; b0 < B_; b0 += nb) {
        int cur = (B_ - b0 < nb) ? (B_ - b0) : nb;
        qk_kernel<<<dim3(C_ / 128, C_ / 128, cur), 256, 0, stream>>>(feat1, feat2, attn, b0);
        softmax_kernel<<<dim3(cur * (C_ / 4)), 256, 0, stream>>>(attn);
        pv_kernel<<<dim3(C_ / 128, HW_ / 64, cur), 256, 0, stream>>>(attn, feat2, feat1, gamma, out, b0);
    }
}

// Round 2
// 203.521 us; speedup vs baseline: 1.3524x; 1.3524x over previous
//
#include <hip/hip_runtime.h>

// Problem constants: B=32, C=768, H=W=24 -> HW=576
#define B_  32
#define C_  768
#define HW_ 576

#define QK_STEPS 18          // HW_/32
#define PV_STEPS 24          // C_/32
#define A_TILE_B 8192        // 128 rows * 64 B per k-step tile
#define V_TILE_B 12288       // 192 rows * 64 B per k-step tile

typedef _Float16 half8 __attribute__((ext_vector_type(8)));
typedef _Float16 half4 __attribute__((ext_vector_type(4)));
typedef float    f32x4 __attribute__((ext_vector_type(4)));

// async global->LDS, 16B per lane; lds base must be wave-uniform
__device__ __forceinline__ void g2l16(const void* g, void* l) {
    __builtin_amdgcn_global_load_lds(
        (const __attribute__((address_space(1))) unsigned int*)g,
        (__attribute__((address_space(3))) unsigned int*)l, 16, 0, 0);
}

// ---------------------------------------------------------------------------
// prep_qk: feat1/feat2 fp32 -> fp16 staged tiles.
// Layout: [bz][tile(6)][k0(18)][row(128)][chunk x(4)][8 halves] with swizzle:
// chunk at position x holds k-elements (x ^ ((row>>1)&3))*8 .. +7.
// One thread per 16B output (handles q AND kv at the same position).
// ---------------------------------------------------------------------------
__global__ __launch_bounds__(256) void prep_qk(const float* __restrict__ f1,
                                               const float* __restrict__ f2,
                                               char* __restrict__ q16,
                                               char* __restrict__ kv16,
                                               int b0) {
    int idx = blockIdx.x * 256 + threadIdx.x;       // < cur*55296 exactly
    int x   = idx & 3;
    int row = (idx >> 2) & 127;
    int t3  = idx >> 9;                             // (bz*6+ti)*18 + k0
    int k0  = t3 % 18;
    int t4  = t3 / 18;
    int ti  = t4 % 6;
    int bz  = t4 / 6;
    int kc  = x ^ ((row >> 1) & 3);
    size_t src = ((size_t)(b0 + bz) * C_ + ti * 128 + row) * HW_ + k0 * 32 + kc * 8;
    f32x4 a0 = *(const f32x4*)(f1 + src);
    f32x4 a1 = *(const f32x4*)(f1 + src + 4);
    f32x4 c0 = *(const f32x4*)(f2 + src);
    f32x4 c1 = *(const f32x4*)(f2 + src + 4);
    half8 ha, hb;
    #pragma unroll
    for (int e = 0; e < 4; ++e) {
        ha[e] = (_Float16)a0[e]; ha[4 + e] = (_Float16)a1[e];
        hb[e] = (_Float16)c0[e]; hb[4 + e] = (_Float16)c1[e];
    }
    *(half8*)(q16  + (size_t)idx * 16) = ha;
    *(half8*)(kv16 + (size_t)idx * 16) = hb;
}

// ---------------------------------------------------------------------------
// prep_vt: feat2 -> transposed fp16 staged tiles for PV's B operand.
// Layout: [bz][tj(3)][k0(24)][n(192)][chunk x(4)][8 halves], element (n,kk)
// = feat2[b][k0*32+kk][tj*192+n], swizzle x holds kk-chunk x^((n>>1)&3).
// Block per (k0,tj,bz): LDS-transpose 32x192 fp32 tile.
// ---------------------------------------------------------------------------
__global__ __launch_bounds__(256) void prep_vt(const float* __restrict__ f2,
                                               char* __restrict__ vt, int b0) {
    __shared__ float Vsh[32 * 201];
    int k0 = blockIdx.x, tj = blockIdx.y, bz = blockIdx.z;
    int b  = b0 + bz;
    int t  = threadIdx.x;
    #pragma unroll
    for (int p = 0; p < 6; ++p) {
        int fidx = p * 256 + t;                 // 0..1535 float4 slots
        int dd = fidx / 48, c4 = fidx % 48;
        f32x4 v = *(const f32x4*)(f2 + ((size_t)b * C_ + k0 * 32 + dd) * HW_ + tj * 192 + c4 * 4);
        #pragma unroll
        for (int e = 0; e < 4; ++e) Vsh[dd * 201 + c4 * 4 + e] = v[e];
    }
    __syncthreads();
    char* ob = vt + ((size_t)(bz * 3 + tj) * PV_STEPS + k0) * V_TILE_B;
    #pragma unroll
    for (int p = 0; p < 3; ++p) {
        int o = p * 256 + t;                    // 0..767
        int x = o & 3, n = o >> 2;
        int kc = x ^ ((n >> 1) & 3);
        half8 h;
        #pragma unroll
        for (int j = 0; j < 8; ++j) h[j] = (_Float16)Vsh[(kc * 8 + j) * 201 + n];
        *(half8*)(ob + o * 16) = h;
    }
}

// ---------------------------------------------------------------------------
// qk2: attn[bz][c][d] = sum_n q[c][n]*kv[d][n], fp16 MFMA, tile 128x128 BK=32.
// Staging via global_load_lds from pre-swizzled q16/kv16.
// ---------------------------------------------------------------------------
__global__ __launch_bounds__(256) void qk2(const char* __restrict__ q16,
                                           const char* __restrict__ kv16,
                                           float* __restrict__ attn) {
    __shared__ __align__(16) char As[A_TILE_B];
    __shared__ __align__(16) char Bs[A_TILE_B];
    const int ti = blockIdx.x, tj = blockIdx.y, bz = blockIdx.z;
    const int t = threadIdx.x, lane = t & 63, w = t >> 6;
    const char* qb = q16  + ((size_t)(bz * 6 + ti) * QK_STEPS) * A_TILE_B + w * 2048 + lane * 16;
    const char* kb = kv16 + ((size_t)(bz * 6 + tj) * QK_STEPS) * A_TILE_B + w * 2048 + lane * 16;
    char* Asw = As + w * 2048;
    char* Bsw = Bs + w * 2048;
    const int wr = (w >> 1) * 64, wc = (w & 1) * 64;
    const int r = lane & 15, cg = lane >> 4;

    int offA[4], offB[4];
    #pragma unroll
    for (int m = 0; m < 4; ++m) {
        int ra = wr + m * 16 + r;
        offA[m] = ra * 64 + ((cg ^ ((ra >> 1) & 3)) << 4);
        int rb = wc + m * 16 + r;
        offB[m] = rb * 64 + ((cg ^ ((rb >> 1) & 3)) << 4);
    }

    f32x4 acc[4][4] = {};
    for (int k0 = 0; k0 < QK_STEPS; ++k0) {
        __syncthreads();
        g2l16(qb + (size_t)k0 * A_TILE_B,        Asw);
        g2l16(qb + (size_t)k0 * A_TILE_B + 1024, Asw + 1024);
        g2l16(kb + (size_t)k0 * A_TILE_B,        Bsw);
        g2l16(kb + (size_t)k0 * A_TILE_B + 1024, Bsw + 1024);
        __syncthreads();
        half8 a[4], bb[4];
        #pragma unroll
        for (int m = 0; m < 4; ++m) a[m]  = *(const half8*)(As + offA[m]);
        #pragma unroll
        for (int n = 0; n < 4; ++n) bb[n] = *(const half8*)(Bs + offB[n]);
        #pragma unroll
        for (int m = 0; m < 4; ++m)
            #pragma unroll
            for (int n = 0; n < 4; ++n)
                acc[m][n] = __builtin_amdgcn_mfma_f32_16x16x32_f16(a[m], bb[n], acc[m][n], 0, 0, 0);
    }

    float* ab = attn + ((size_t)bz * C_ + ti * 128) * C_ + tj * 128;
    const int col = lane & 15, rbase = (lane >> 4) * 4;
    #pragma unroll
    for (int m = 0; m < 4; ++m)
        #pragma unroll
        for (int n = 0; n < 4; ++n)
            #pragma unroll
            for (int rg = 0; rg < 4; ++rg)
                ab[(size_t)(wr + m * 16 + rbase + rg) * C_ + wc + n * 16 + col] = acc[m][n][rg];
}

// ---------------------------------------------------------------------------
// softmax_p16: row softmax of attn (fp32), writes P as fp16 in the staged
// swizzled tile layout, with gamma folded in. One wave per row.
// ---------------------------------------------------------------------------
__global__ __launch_bounds__(256) void softmax_p16(const float* __restrict__ attn,
                                                   char* __restrict__ p16,
                                                   const float* __restrict__ gamma) {
    const int R    = blockIdx.x * 4 + (threadIdx.x >> 6);   // chunk-local row
    const int lane = threadIdx.x & 63;
    const int bz   = R / C_;
    const int c    = R - bz * C_;
    const float* p = attn + (size_t)R * C_;

    f32x4 v[3];
    float mx = -1e30f;
    #pragma unroll
    for (int u = 0; u < 3; ++u) {
        v[u] = *(const f32x4*)(p + (size_t)(lane + 64 * u) * 4);
        #pragma unroll
        for (int e = 0; e < 4; ++e) mx = fmaxf(mx, v[u][e]);
    }
    #pragma unroll
    for (int o = 32; o > 0; o >>= 1) mx = fmaxf(mx, __shfl_xor(mx, o));

    float s = 0.f;
    #pragma unroll
    for (int u = 0; u < 3; ++u)
        #pragma unroll
        for (int e = 0; e < 4; ++e) {
            v[u][e] = __expf(v[u][e] - mx);
            s += v[u][e];
        }
    #pragma unroll
    for (int o = 32; o > 0; o >>= 1) s += __shfl_xor(s, o);
    const float scale = gamma[0] / s;

    const int sw = (c >> 1) & 3;
    char* tb = p16 + ((size_t)(bz * 6 + (c >> 7)) * PV_STEPS) * A_TILE_B;
    #pragma unroll
    for (int u = 0; u < 3; ++u) {
        int d0 = 4 * lane + 256 * u;
        int k0 = d0 >> 5;
        int x  = ((d0 >> 3) & 3) ^ sw;
        char* addr = tb + (size_t)k0 * A_TILE_B + (c & 127) * 64 + x * 16 + (d0 & 7) * 2;
        half4 hv;
        #pragma unroll
        for (int e = 0; e < 4; ++e) hv[e] = (_Float16)(v[u][e] * scale);
        *(half4*)addr = hv;
    }
}

// ---------------------------------------------------------------------------
// pv2: out = (gamma*P)@V + feat1. Tile 128x192, BK=32, fp16 MFMA.
// A from p16 (staged), B from vt (staged transposed V).
// ---------------------------------------------------------------------------
__global__ __launch_bounds__(256) void pv2(const char* __restrict__ p16,
                                           const char* __restrict__ vt,
                                           const float* __restrict__ f1,
                                           float* __restrict__ out, int b0) {
    __shared__ __align__(16) char Ps[A_TILE_B];
    __shared__ __align__(16) char Vs[V_TILE_B];
    const int ti = blockIdx.x, tj = blockIdx.y, bz = blockIdx.z;
    const int t = threadIdx.x, lane = t & 63, w = t >> 6;
    const char* pb = p16 + ((size_t)(bz * 6 + ti) * PV_STEPS) * A_TILE_B + w * 2048 + lane * 16;
    const char* vb = vt  + ((size_t)(bz * 3 + tj) * PV_STEPS) * V_TILE_B + w * 3072 + lane * 16;
    char* Psw = Ps + w * 2048;
    char* Vsw = Vs + w * 3072;
    const int wr = (w >> 1) * 64, wc = (w & 1) * 96;
    const int r = lane & 15, cg = lane >> 4;

    int offA[4], offB[6];
    #pragma unroll
    for (int m = 0; m < 4; ++m) {
        int ra = wr + m * 16 + r;
        offA[m] = ra * 64 + ((cg ^ ((ra >> 1) & 3)) << 4);
    }
    #pragma unroll
    for (int n = 0; n < 6; ++n) {
        int rb = wc + n * 16 + r;
        offB[n] = rb * 64 + ((cg ^ ((rb >> 1) & 3)) << 4);
    }

    f32x4 acc[4][6] = {};
    for (int k0 = 0; k0 < PV_STEPS; ++k0) {
        __syncthreads();
        g2l16(pb + (size_t)k0 * A_TILE_B,        Psw);
        g2l16(pb + (size_t)k0 * A_TILE_B + 1024, Psw + 1024);
        g2l16(vb + (size_t)k0 * V_TILE_B,        Vsw);
        g2l16(vb + (size_t)k0 * V_TILE_B + 1024, Vsw + 1024);
        g2l16(vb + (size_t)k0 * V_TILE_B + 2048, Vsw + 2048);
        __syncthreads();
        half8 a[4], bb[6];
        #pragma unroll
        for (int m = 0; m < 4; ++m) a[m]  = *(const half8*)(Ps + offA[m]);
        #pragma unroll
        for (int n = 0; n < 6; ++n) bb[n] = *(const half8*)(Vs + offB[n]);
        #pragma unroll
        for (int m = 0; m < 4; ++m)
            #pragma unroll
            for (int n = 0; n < 6; ++n)
                acc[m][n] = __builtin_amdgcn_mfma_f32_16x16x32_f16(a[m], bb[n], acc[m][n], 0, 0, 0);
    }

    const int b = b0 + bz;
    const float* f1b = f1 + ((size_t)b * C_ + ti * 128) * HW_ + tj * 192;
    float*       ob  = out + ((size_t)b * C_ + ti * 128) * HW_ + tj * 192;
    const int col = lane & 15, rbase = (lane >> 4) * 4;
    #pragma unroll
    for (int m = 0; m < 4; ++m)
        #pragma unroll
        for (int n = 0; n < 6; ++n)
            #pragma unroll
            for (int rg = 0; rg < 4; ++rg) {
                int rr = wr + m * 16 + rbase + rg;
                int cc = wc + n * 16 + col;
                ob[(size_t)rr * HW_ + cc] = acc[m][n][rg] + f1b[(size_t)rr * HW_ + cc];
            }
}

// ---------------------------------------------------------------------------
extern "C" void kernel_launch(void* const* d_in, const int* in_sizes, int n_in,
                              void* d_out, int out_size, void* d_ws, size_t ws_size,
                              hipStream_t stream) {
    const float* feat1 = (const float*)d_in[0];
    const float* feat2 = (const float*)d_in[1];
    const float* gamma = (const float*)d_in[2];
    float* out = (float*)d_out;

    const size_t SZ_Q    = (size_t)C_ * HW_ * 2;   //   884,736 B/batch
    const size_t SZ_ATTN = (size_t)C_ * C_  * 4;   // 2,359,296 B/batch
    const size_t SZ_P    = (size_t)C_ * C_  * 2;   // 1,179,648 B/batch
    const size_t per_batch = SZ_ATTN + 3 * SZ_Q + SZ_P;  // 6,193,152

    int nb = (int)(ws_size / per_batch);
    if (nb < 1) nb = 1;
    if (nb > B_) nb = B_;

    char* ws   = (char*)d_ws;
    float* attn = (float*)ws;
    char* q16  = ws + (size_t)nb * SZ_ATTN;
    char* kv16 = q16 + (size_t)nb * SZ_Q;
    char* vtb  = kv16 + (size_t)nb * SZ_Q;
    char* p16  = vtb + (size_t)nb * SZ_Q;

    for (int b0 = 0; b0 < B_; b0 += nb) {
        int cur = (B_ - b0 < nb) ? (B_ - b0) : nb;
        prep_qk<<<cur * 216, 256, 0, stream>>>(feat1, feat2, q16, kv16, b0);
        prep_vt<<<dim3(PV_STEPS, 3, cur), 256, 0, stream>>>(feat2, vtb, b0);
        qk2<<<dim3(6, 6, cur), 256, 0, stream>>>(q16, kv16, attn);
        softmax_p16<<<cur * (C_ / 4), 256, 0, stream>>>(attn, p16, gamma);
        pv2<<<dim3(6, 3, cur), 256, 0, stream>>>(p16, vtb, feat1, out, b0);
    }
}

// Round 3
// 200.294 us; speedup vs baseline: 1.3741x; 1.0161x over previous
//
#include <hip/hip_runtime.h>

// Problem constants: B=32, C=768, H=W=24 -> HW=576
#define B_  32
#define C_  768
#define HW_ 576

#define QK_STEPS 18          // HW_/32 k-chunks
#define PV_STEPS 24          // C_/32 k-chunks
#define A_TILE_B 8192        // 128 rows * 64 B per 32-k chunk
#define V_TILE_B 12288       // 192 rows * 64 B per 32-k chunk

typedef _Float16 half8 __attribute__((ext_vector_type(8)));
typedef _Float16 half4 __attribute__((ext_vector_type(4)));
typedef float    f32x4 __attribute__((ext_vector_type(4)));

// async global->LDS, 16B per lane; lds base wave-uniform, global src per-lane
__device__ __forceinline__ void g2l16(const void* g, void* l) {
    __builtin_amdgcn_global_load_lds(
        (const __attribute__((address_space(1))) unsigned int*)g,
        (__attribute__((address_space(3))) unsigned int*)l, 16, 0, 0);
}

// bijective XCD-aware block swizzle (m204): each XCD gets a contiguous
// work-id chunk so neighbor tiles share its L2.
__device__ __forceinline__ int xcd_swz(int orig, int nwg) {
    int q = nwg >> 3, rr = nwg & 7;
    int xcd = orig & 7, idx = orig >> 3;
    int base = (xcd < rr) ? xcd * (q + 1) : rr * (q + 1) + (xcd - rr) * q;
    return base + idx;
}

// ---------------------------------------------------------------------------
// prep_qk: feat1/feat2 fp32 -> fp16 staged tiles.
// Layout: [bz][tile(6)][k0(18)][row(128)][chunk x(4)][8 halves], swizzle:
// chunk x holds k-elements (x ^ ((row>>1)&3))*8 .. +7.
// ---------------------------------------------------------------------------
__global__ __launch_bounds__(256) void prep_qk(const float* __restrict__ f1,
                                               const float* __restrict__ f2,
                                               char* __restrict__ q16,
                                               char* __restrict__ kv16,
                                               int b0) {
    int idx = blockIdx.x * 256 + threadIdx.x;       // < cur*55296 exactly
    int x   = idx & 3;
    int row = (idx >> 2) & 127;
    int t3  = idx >> 9;
    int k0  = t3 % 18;
    int t4  = t3 / 18;
    int ti  = t4 % 6;
    int bz  = t4 / 6;
    int kc  = x ^ ((row >> 1) & 3);
    size_t src = ((size_t)(b0 + bz) * C_ + ti * 128 + row) * HW_ + k0 * 32 + kc * 8;
    f32x4 a0 = *(const f32x4*)(f1 + src);
    f32x4 a1 = *(const f32x4*)(f1 + src + 4);
    f32x4 c0 = *(const f32x4*)(f2 + src);
    f32x4 c1 = *(const f32x4*)(f2 + src + 4);
    half8 ha, hb;
    #pragma unroll
    for (int e = 0; e < 4; ++e) {
        ha[e] = (_Float16)a0[e]; ha[4 + e] = (_Float16)a1[e];
        hb[e] = (_Float16)c0[e]; hb[4 + e] = (_Float16)c1[e];
    }
    *(half8*)(q16  + (size_t)idx * 16) = ha;
    *(half8*)(kv16 + (size_t)idx * 16) = hb;
}

// ---------------------------------------------------------------------------
// prep_vt: feat2 -> transposed fp16 tiles for PV's B operand.
// Layout: [bz][tj(3)][k0(24)][n(192)][chunk x(4)][8], elem (n,kk) =
// feat2[b][k0*32+kk][tj*192+n], swizzle x^((n>>1)&3).
// ---------------------------------------------------------------------------
__global__ __launch_bounds__(256) void prep_vt(const float* __restrict__ f2,
                                               char* __restrict__ vt, int b0) {
    __shared__ float Vsh[32 * 201];
    int k0 = blockIdx.x, tj = blockIdx.y, bz = blockIdx.z;
    int b  = b0 + bz;
    int t  = threadIdx.x;
    #pragma unroll
    for (int p = 0; p < 6; ++p) {
        int fidx = p * 256 + t;
        int dd = fidx / 48, c4 = fidx % 48;
        f32x4 v = *(const f32x4*)(f2 + ((size_t)b * C_ + k0 * 32 + dd) * HW_ + tj * 192 + c4 * 4);
        #pragma unroll
        for (int e = 0; e < 4; ++e) Vsh[dd * 201 + c4 * 4 + e] = v[e];
    }
    __syncthreads();
    char* ob = vt + ((size_t)(bz * 3 + tj) * PV_STEPS + k0) * V_TILE_B;
    #pragma unroll
    for (int p = 0; p < 3; ++p) {
        int o = p * 256 + t;
        int x = o & 3, n = o >> 2;
        int kc = x ^ ((n >> 1) & 3);
        half8 h;
        #pragma unroll
        for (int j = 0; j < 8; ++j) h[j] = (_Float16)Vsh[(kc * 8 + j) * 201 + n];
        *(half8*)(ob + o * 16) = h;
    }
}

// ---------------------------------------------------------------------------
// qk2: attn = q @ kv^T per batch. Tile 128x128, BK=64, 8 waves (2Mx4N),
// 2-phase double-buffered global_load_lds pipeline.
// ---------------------------------------------------------------------------
__global__ __launch_bounds__(512, 4) void qk2(const char* __restrict__ q16,
                                              const char* __restrict__ kv16,
                                              float* __restrict__ attn,
                                              int nwg) {
    __shared__ __align__(16) char As[2][16384];
    __shared__ __align__(16) char Bs[2][16384];
    const int wg = xcd_swz(blockIdx.x, nwg);
    const int tj = wg % 6, tmp = wg / 6, ti = tmp % 6, bz = tmp / 6;
    const int t = threadIdx.x, lane = t & 63, w = t >> 6;

    const char* qt = q16  + ((size_t)(bz * 6 + ti) * QK_STEPS) * A_TILE_B + w * 1024 + lane * 16;
    const char* kt = kv16 + ((size_t)(bz * 6 + tj) * QK_STEPS) * A_TILE_B + w * 1024 + lane * 16;

    const int wr = (w >> 2) * 64, wc = (w & 3) * 32;
    const int r = lane & 15, cg = lane >> 4;
    int offA[4], offB[2];
    #pragma unroll
    for (int m = 0; m < 4; ++m) {
        int ra = wr + m * 16 + r;
        offA[m] = ra * 64 + ((cg ^ ((ra >> 1) & 3)) << 4);
    }
    #pragma unroll
    for (int n = 0; n < 2; ++n) {
        int rb = wc + n * 16 + r;
        offB[n] = rb * 64 + ((cg ^ ((rb >> 1) & 3)) << 4);
    }

    f32x4 acc[4][2] = {};

#define QSTAGE(it, bb) do {                                        \
        g2l16(qt + (it) * 16384,        &As[bb][w * 1024]);        \
        g2l16(qt + (it) * 16384 + 8192, &As[bb][w * 1024 + 8192]); \
        g2l16(kt + (it) * 16384,        &Bs[bb][w * 1024]);        \
        g2l16(kt + (it) * 16384 + 8192, &Bs[bb][w * 1024 + 8192]); \
    } while (0)

    QSTAGE(0, 0);
    for (int it = 0; it < 9; ++it) {
        const int cur = it & 1;
        __syncthreads();                 // drains vmcnt: buf[cur] ready
        if (it < 8) QSTAGE(it + 1, cur ^ 1);
        #pragma unroll
        for (int c = 0; c < 2; ++c) {
            half8 a[4], bb8[2];
            #pragma unroll
            for (int m = 0; m < 4; ++m) a[m]  = *(const half8*)(&As[cur][c * 8192 + offA[m]]);
            #pragma unroll
            for (int n = 0; n < 2; ++n) bb8[n] = *(const half8*)(&Bs[cur][c * 8192 + offB[n]]);
            #pragma unroll
            for (int m = 0; m < 4; ++m)
                #pragma unroll
                for (int n = 0; n < 2; ++n)
                    acc[m][n] = __builtin_amdgcn_mfma_f32_16x16x32_f16(a[m], bb8[n], acc[m][n], 0, 0, 0);
        }
    }
#undef QSTAGE

    float* ab = attn + ((size_t)bz * C_ + ti * 128) * C_ + tj * 128;
    const int col = lane & 15, rbase = (lane >> 4) * 4;
    #pragma unroll
    for (int m = 0; m < 4; ++m)
        #pragma unroll
        for (int n = 0; n < 2; ++n)
            #pragma unroll
            for (int rg = 0; rg < 4; ++rg)
                ab[(size_t)(wr + m * 16 + rbase + rg) * C_ + wc + n * 16 + col] = acc[m][n][rg];
}

// ---------------------------------------------------------------------------
// softmax_p16: row softmax of attn (fp32) -> P fp16 in staged swizzled tile
// layout, gamma folded in. One wave per row.
// ---------------------------------------------------------------------------
__global__ __launch_bounds__(256) void softmax_p16(const float* __restrict__ attn,
                                                   char* __restrict__ p16,
                                                   const float* __restrict__ gamma) {
    const int R    = blockIdx.x * 4 + (threadIdx.x >> 6);
    const int lane = threadIdx.x & 63;
    const int bz   = R / C_;
    const int c    = R - bz * C_;
    const float* p = attn + (size_t)R * C_;

    f32x4 v[3];
    float mx = -1e30f;
    #pragma unroll
    for (int u = 0; u < 3; ++u) {
        v[u] = *(const f32x4*)(p + (size_t)(lane + 64 * u) * 4);
        #pragma unroll
        for (int e = 0; e < 4; ++e) mx = fmaxf(mx, v[u][e]);
    }
    #pragma unroll
    for (int o = 32; o > 0; o >>= 1) mx = fmaxf(mx, __shfl_xor(mx, o));

    float s = 0.f;
    #pragma unroll
    for (int u = 0; u < 3; ++u)
        #pragma unroll
        for (int e = 0; e < 4; ++e) {
            v[u][e] = __expf(v[u][e] - mx);
            s += v[u][e];
        }
    #pragma unroll
    for (int o = 32; o > 0; o >>= 1) s += __shfl_xor(s, o);
    const float scale = gamma[0] / s;

    const int sw = (c >> 1) & 3;
    char* tb = p16 + ((size_t)(bz * 6 + (c >> 7)) * PV_STEPS) * A_TILE_B;
    #pragma unroll
    for (int u = 0; u < 3; ++u) {
        int d0 = 4 * lane + 256 * u;
        int k0 = d0 >> 5;
        int x  = ((d0 >> 3) & 3) ^ sw;
        char* addr = tb + (size_t)k0 * A_TILE_B + (c & 127) * 64 + x * 16 + (d0 & 7) * 2;
        half4 hv;
        #pragma unroll
        for (int e = 0; e < 4; ++e) hv[e] = (_Float16)(v[u][e] * scale);
        *(half4*)addr = hv;
    }
}

// ---------------------------------------------------------------------------
// pv2: out = (gamma*P)@V + feat1. Tile 128x192, BK=64, 8 waves (2Mx4N),
// 2-phase double-buffered pipeline. LDS 80 KB -> 2 blocks/CU.
// ---------------------------------------------------------------------------
__global__ __launch_bounds__(512, 4) void pv2(const char* __restrict__ p16,
                                              const char* __restrict__ vt,
                                              const float* __restrict__ f1,
                                              float* __restrict__ out,
                                              int b0, int nwg) {
    __shared__ __align__(16) char Ps[2][16384];
    __shared__ __align__(16) char Vs[2][24576];
    const int wg = xcd_swz(blockIdx.x, nwg);
    const int tj = wg % 3, tmp = wg / 3, ti = tmp % 6, bz = tmp / 6;
    const int t = threadIdx.x, lane = t & 63, w = t >> 6;

    const char* pt = p16 + ((size_t)(bz * 6 + ti) * PV_STEPS) * A_TILE_B + w * 1024 + lane * 16;
    const char* vb = vt  + ((size_t)(bz * 3 + tj) * PV_STEPS) * V_TILE_B + w * 1024 + lane * 16;

    const int wr = (w >> 2) * 64, wc = (w & 3) * 48;
    const int r = lane & 15, cg = lane >> 4;
    int offA[4], offB[3];
    #pragma unroll
    for (int m = 0; m < 4; ++m) {
        int ra = wr + m * 16 + r;
        offA[m] = ra * 64 + ((cg ^ ((ra >> 1) & 3)) << 4);
    }
    #pragma unroll
    for (int n = 0; n < 3; ++n) {
        int rb = wc + n * 16 + r;
        offB[n] = rb * 64 + ((cg ^ ((rb >> 1) & 3)) << 4);
    }

    f32x4 acc[4][3] = {};

#define PSTAGE(it, bb) do {                                          \
        g2l16(pt + (it) * 16384,         &Ps[bb][w * 1024]);         \
        g2l16(pt + (it) * 16384 + 8192,  &Ps[bb][w * 1024 + 8192]);  \
        g2l16(vb + (it) * 24576,         &Vs[bb][w * 1024]);         \
        g2l16(vb + (it) * 24576 + 8192,  &Vs[bb][w * 1024 + 8192]);  \
        g2l16(vb + (it) * 24576 + 16384, &Vs[bb][w * 1024 + 16384]); \
    } while (0)

    PSTAGE(0, 0);
    for (int it = 0; it < 12; ++it) {
        const int cur = it & 1;
        __syncthreads();                 // drains vmcnt: buf[cur] ready
        if (it < 11) PSTAGE(it + 1, cur ^ 1);
        #pragma unroll
        for (int c = 0; c < 2; ++c) {
            half8 a[4], bb8[3];
            #pragma unroll
            for (int m = 0; m < 4; ++m) a[m]  = *(const half8*)(&Ps[cur][c * 8192 + offA[m]]);
            #pragma unroll
            for (int n = 0; n < 3; ++n) bb8[n] = *(const half8*)(&Vs[cur][c * 12288 + offB[n]]);
            #pragma unroll
            for (int m = 0; m < 4; ++m)
                #pragma unroll
                for (int n = 0; n < 3; ++n)
                    acc[m][n] = __builtin_amdgcn_mfma_f32_16x16x32_f16(a[m], bb8[n], acc[m][n], 0, 0, 0);
        }
    }
#undef PSTAGE

    const int b = b0 + bz;
    const float* f1b = f1 + ((size_t)b * C_ + ti * 128) * HW_ + tj * 192;
    float*       ob  = out + ((size_t)b * C_ + ti * 128) * HW_ + tj * 192;
    const int col = lane & 15, rbase = (lane >> 4) * 4;
    #pragma unroll
    for (int m = 0; m < 4; ++m)
        #pragma unroll
        for (int n = 0; n < 3; ++n)
            #pragma unroll
            for (int rg = 0; rg < 4; ++rg) {
                int rr = wr + m * 16 + rbase + rg;
                int cc = wc + n * 16 + col;
                ob[(size_t)rr * HW_ + cc] = acc[m][n][rg] + f1b[(size_t)rr * HW_ + cc];
            }
}

// ---------------------------------------------------------------------------
extern "C" void kernel_launch(void* const* d_in, const int* in_sizes, int n_in,
                              void* d_out, int out_size, void* d_ws, size_t ws_size,
                              hipStream_t stream) {
    const float* feat1 = (const float*)d_in[0];
    const float* feat2 = (const float*)d_in[1];
    const float* gamma = (const float*)d_in[2];
    float* out = (float*)d_out;

    const size_t SZ_Q    = (size_t)C_ * HW_ * 2;   //   884,736 B/batch
    const size_t SZ_ATTN = (size_t)C_ * C_  * 4;   // 2,359,296 B/batch
    const size_t SZ_P    = (size_t)C_ * C_  * 2;   // 1,179,648 B/batch
    const size_t per_batch = SZ_ATTN + 3 * SZ_Q + SZ_P;

    int nb = (int)(ws_size / per_batch);
    if (nb < 1) nb = 1;
    if (nb > B_) nb = B_;

    char* ws    = (char*)d_ws;
    float* attn = (float*)ws;
    char* q16   = ws + (size_t)nb * SZ_ATTN;
    char* kv16  = q16 + (size_t)nb * SZ_Q;
    char* vtb   = kv16 + (size_t)nb * SZ_Q;
    char* p16   = vtb + (size_t)nb * SZ_Q;

    for (int b0 = 0; b0 < B_; b0 += nb) {
        int cur = (B_ - b0 < nb) ? (B_ - b0) : nb;
        prep_qk<<<cur * 216, 256, 0, stream>>>(feat1, feat2, q16, kv16, b0);
        prep_vt<<<dim3(PV_STEPS, 3, cur), 256, 0, stream>>>(feat2, vtb, b0);
        qk2<<<cur * 36, 512, 0, stream>>>(q16, kv16, attn, cur * 36);
        softmax_p16<<<cur * (C_ / 4), 256, 0, stream>>>(attn, p16, gamma);
        pv2<<<cur * 18, 512, 0, stream>>>(p16, vtb, feat1, out, b0, cur * 18);
    }
}

// Round 4
// 188.811 us; speedup vs baseline: 1.4577x; 1.0608x over previous
//
#include <hip/hip_runtime.h>

// Problem constants: B=32, C=768, H=W=24 -> HW=576
#define B_  32
#define C_  768
#define HW_ 576

#define QK_STEPS 18          // HW_/32 k-chunks
#define PV_STEPS 24          // C_/32 k-chunks
#define A_TILE_B 8192        // 128 rows * 64 B per 32-k chunk
#define V_TILE_B 12288       // 192 rows * 64 B per 32-k chunk

typedef _Float16 half8 __attribute__((ext_vector_type(8)));
typedef _Float16 half4 __attribute__((ext_vector_type(4)));
typedef float    f32x4 __attribute__((ext_vector_type(4)));

// async global->LDS, 16B per lane; lds base wave-uniform, global src per-lane
__device__ __forceinline__ void g2l16(const void* g, void* l) {
    __builtin_amdgcn_global_load_lds(
        (const __attribute__((address_space(1))) unsigned int*)g,
        (__attribute__((address_space(3))) unsigned int*)l, 16, 0, 0);
}

// bijective XCD-aware block swizzle (m204)
__device__ __forceinline__ int xcd_swz(int orig, int nwg) {
    int q = nwg >> 3, rr = nwg & 7;
    int xcd = orig & 7, idx = orig >> 3;
    int base = (xcd < rr) ? xcd * (q + 1) : rr * (q + 1) + (xcd - rr) * q;
    return base + idx;
}

// counted-vmcnt pipeline sync primitives (T3+T4)
#define LGKM0_BARRIER() do {                                   \
        asm volatile("s_waitcnt lgkmcnt(0)" ::: "memory");     \
        __builtin_amdgcn_s_barrier();                          \
    } while (0)
#define VMCNT_BARRIER(N) do {                                  \
        asm volatile("s_waitcnt vmcnt(" #N ")" ::: "memory");  \
        __builtin_amdgcn_s_barrier();                          \
    } while (0)

// ---------------------------------------------------------------------------
// prep_qk: feat1/feat2 fp32 -> fp16 staged tiles.
// Layout: [bz][tile(6)][k0(18)][row(128)][chunk x(4)][8 halves], swizzle:
// chunk x holds k-elements (x ^ ((row>>1)&3))*8 .. +7.
// ---------------------------------------------------------------------------
__global__ __launch_bounds__(256) void prep_qk(const float* __restrict__ f1,
                                               const float* __restrict__ f2,
                                               char* __restrict__ q16,
                                               char* __restrict__ kv16,
                                               int b0) {
    int idx = blockIdx.x * 256 + threadIdx.x;
    int x   = idx & 3;
    int row = (idx >> 2) & 127;
    int t3  = idx >> 9;
    int k0  = t3 % 18;
    int t4  = t3 / 18;
    int ti  = t4 % 6;
    int bz  = t4 / 6;
    int kc  = x ^ ((row >> 1) & 3);
    size_t src = ((size_t)(b0 + bz) * C_ + ti * 128 + row) * HW_ + k0 * 32 + kc * 8;
    f32x4 a0 = *(const f32x4*)(f1 + src);
    f32x4 a1 = *(const f32x4*)(f1 + src + 4);
    f32x4 c0 = *(const f32x4*)(f2 + src);
    f32x4 c1 = *(const f32x4*)(f2 + src + 4);
    half8 ha, hb;
    #pragma unroll
    for (int e = 0; e < 4; ++e) {
        ha[e] = (_Float16)a0[e]; ha[4 + e] = (_Float16)a1[e];
        hb[e] = (_Float16)c0[e]; hb[4 + e] = (_Float16)c1[e];
    }
    *(half8*)(q16  + (size_t)idx * 16) = ha;
    *(half8*)(kv16 + (size_t)idx * 16) = hb;
}

// ---------------------------------------------------------------------------
// prep_vt: feat2 -> transposed fp16 tiles for PV's B operand.
// ---------------------------------------------------------------------------
__global__ __launch_bounds__(256) void prep_vt(const float* __restrict__ f2,
                                               char* __restrict__ vt, int b0) {
    __shared__ float Vsh[32 * 201];
    int k0 = blockIdx.x, tj = blockIdx.y, bz = blockIdx.z;
    int b  = b0 + bz;
    int t  = threadIdx.x;
    #pragma unroll
    for (int p = 0; p < 6; ++p) {
        int fidx = p * 256 + t;
        int dd = fidx / 48, c4 = fidx % 48;
        f32x4 v = *(const f32x4*)(f2 + ((size_t)b * C_ + k0 * 32 + dd) * HW_ + tj * 192 + c4 * 4);
        #pragma unroll
        for (int e = 0; e < 4; ++e) Vsh[dd * 201 + c4 * 4 + e] = v[e];
    }
    __syncthreads();
    char* ob = vt + ((size_t)(bz * 3 + tj) * PV_STEPS + k0) * V_TILE_B;
    #pragma unroll
    for (int p = 0; p < 3; ++p) {
        int o = p * 256 + t;
        int x = o & 3, n = o >> 2;
        int kc = x ^ ((n >> 1) & 3);
        half8 h;
        #pragma unroll
        for (int j = 0; j < 8; ++j) h[j] = (_Float16)Vsh[(kc * 8 + j) * 201 + n];
        *(half8*)(ob + o * 16) = h;
    }
}

// ---------------------------------------------------------------------------
// qk2: attn = q @ kv^T. Tile 128x128, BK=64, 8 waves, counted-vmcnt pipeline.
// ---------------------------------------------------------------------------
__global__ __launch_bounds__(512, 4) void qk2(const char* __restrict__ q16,
                                              const char* __restrict__ kv16,
                                              float* __restrict__ attn,
                                              int nwg) {
    __shared__ __align__(16) char As[2][16384];
    __shared__ __align__(16) char Bs[2][16384];
    const int wg = xcd_swz(blockIdx.x, nwg);
    const int tj = wg % 6, tmp = wg / 6, ti = tmp % 6, bz = tmp / 6;
    const int t = threadIdx.x, lane = t & 63, w = t >> 6;

    const char* qt = q16  + ((size_t)(bz * 6 + ti) * QK_STEPS) * A_TILE_B + w * 1024 + lane * 16;
    const char* kt = kv16 + ((size_t)(bz * 6 + tj) * QK_STEPS) * A_TILE_B + w * 1024 + lane * 16;

    const int wr = (w >> 2) * 64, wc = (w & 3) * 32;
    const int r = lane & 15, cg = lane >> 4;
    int offA[4], offB[2];
    #pragma unroll
    for (int m = 0; m < 4; ++m) {
        int ra = wr + m * 16 + r;
        offA[m] = ra * 64 + ((cg ^ ((ra >> 1) & 3)) << 4);
    }
    #pragma unroll
    for (int n = 0; n < 2; ++n) {
        int rb = wc + n * 16 + r;
        offB[n] = rb * 64 + ((cg ^ ((rb >> 1) & 3)) << 4);
    }

    f32x4 acc[4][2] = {};

#define QSTAGE(it, bb) do {                                        \
        g2l16(qt + (it) * 16384,        &As[bb][w * 1024]);        \
        g2l16(qt + (it) * 16384 + 8192, &As[bb][w * 1024 + 8192]); \
        g2l16(kt + (it) * 16384,        &Bs[bb][w * 1024]);        \
        g2l16(kt + (it) * 16384 + 8192, &Bs[bb][w * 1024 + 8192]); \
    } while (0)

    QSTAGE(0, 0);
    for (int it = 0; it < 9; ++it) {
        const int cur = it & 1;
        LGKM0_BARRIER();                 // all waves done reading buf[cur^1]
        if (it < 8) {
            QSTAGE(it + 1, cur ^ 1);     // 4 loads/wave, stay in flight
            VMCNT_BARRIER(4);            // stage(it) landed everywhere
        } else {
            VMCNT_BARRIER(0);
        }
        #pragma unroll
        for (int c = 0; c < 2; ++c) {
            half8 a[4], bb8[2];
            #pragma unroll
            for (int m = 0; m < 4; ++m) a[m]  = *(const half8*)(&As[cur][c * 8192 + offA[m]]);
            #pragma unroll
            for (int n = 0; n < 2; ++n) bb8[n] = *(const half8*)(&Bs[cur][c * 8192 + offB[n]]);
            #pragma unroll
            for (int m = 0; m < 4; ++m)
                #pragma unroll
                for (int n = 0; n < 2; ++n)
                    acc[m][n] = __builtin_amdgcn_mfma_f32_16x16x32_f16(a[m], bb8[n], acc[m][n], 0, 0, 0);
        }
    }
#undef QSTAGE

    float* ab = attn + ((size_t)bz * C_ + ti * 128) * C_ + tj * 128;
    const int col = lane & 15, rbase = (lane >> 4) * 4;
    #pragma unroll
    for (int m = 0; m < 4; ++m)
        #pragma unroll
        for (int n = 0; n < 2; ++n)
            #pragma unroll
            for (int rg = 0; rg < 4; ++rg)
                ab[(size_t)(wr + m * 16 + rbase + rg) * C_ + wc + n * 16 + col] = acc[m][n][rg];
}

// ---------------------------------------------------------------------------
// softmax_p16: row softmax of attn (fp32) -> P fp16 staged layout, gamma folded.
// ---------------------------------------------------------------------------
__global__ __launch_bounds__(256) void softmax_p16(const float* __restrict__ attn,
                                                   char* __restrict__ p16,
                                                   const float* __restrict__ gamma) {
    const int R    = blockIdx.x * 4 + (threadIdx.x >> 6);
    const int lane = threadIdx.x & 63;
    const int bz   = R / C_;
    const int c    = R - bz * C_;
    const float* p = attn + (size_t)R * C_;

    f32x4 v[3];
    float mx = -1e30f;
    #pragma unroll
    for (int u = 0; u < 3; ++u) {
        v[u] = *(const f32x4*)(p + (size_t)(lane + 64 * u) * 4);
        #pragma unroll
        for (int e = 0; e < 4; ++e) mx = fmaxf(mx, v[u][e]);
    }
    #pragma unroll
    for (int o = 32; o > 0; o >>= 1) mx = fmaxf(mx, __shfl_xor(mx, o));

    float s = 0.f;
    #pragma unroll
    for (int u = 0; u < 3; ++u)
        #pragma unroll
        for (int e = 0; e < 4; ++e) {
            v[u][e] = __expf(v[u][e] - mx);
            s += v[u][e];
        }
    #pragma unroll
    for (int o = 32; o > 0; o >>= 1) s += __shfl_xor(s, o);
    const float scale = gamma[0] / s;

    const int sw = (c >> 1) & 3;
    char* tb = p16 + ((size_t)(bz * 6 + (c >> 7)) * PV_STEPS) * A_TILE_B;
    #pragma unroll
    for (int u = 0; u < 3; ++u) {
        int d0 = 4 * lane + 256 * u;
        int k0 = d0 >> 5;
        int x  = ((d0 >> 3) & 3) ^ sw;
        char* addr = tb + (size_t)k0 * A_TILE_B + (c & 127) * 64 + x * 16 + (d0 & 7) * 2;
        half4 hv;
        #pragma unroll
        for (int e = 0; e < 4; ++e) hv[e] = (_Float16)(v[u][e] * scale);
        *(half4*)addr = hv;
    }
}

// ---------------------------------------------------------------------------
// pv2: out = (gamma*P)@V + feat1. Tile 128x192, BK=64, 8 waves,
// counted-vmcnt pipeline.
// ---------------------------------------------------------------------------
__global__ __launch_bounds__(512, 4) void pv2(const char* __restrict__ p16,
                                              const char* __restrict__ vt,
                                              const float* __restrict__ f1,
                                              float* __restrict__ out,
                                              int b0, int nwg) {
    __shared__ __align__(16) char Ps[2][16384];
    __shared__ __align__(16) char Vs[2][24576];
    const int wg = xcd_swz(blockIdx.x, nwg);
    const int tj = wg % 3, tmp = wg / 3, ti = tmp % 6, bz = tmp / 6;
    const int t = threadIdx.x, lane = t & 63, w = t >> 6;

    const char* pt = p16 + ((size_t)(bz * 6 + ti) * PV_STEPS) * A_TILE_B + w * 1024 + lane * 16;
    const char* vb = vt  + ((size_t)(bz * 3 + tj) * PV_STEPS) * V_TILE_B + w * 1024 + lane * 16;

    const int wr = (w >> 2) * 64, wc = (w & 3) * 48;
    const int r = lane & 15, cg = lane >> 4;
    int offA[4], offB[3];
    #pragma unroll
    for (int m = 0; m < 4; ++m) {
        int ra = wr + m * 16 + r;
        offA[m] = ra * 64 + ((cg ^ ((ra >> 1) & 3)) << 4);
    }
    #pragma unroll
    for (int n = 0; n < 3; ++n) {
        int rb = wc + n * 16 + r;
        offB[n] = rb * 64 + ((cg ^ ((rb >> 1) & 3)) << 4);
    }

    f32x4 acc[4][3] = {};

#define PSTAGE(it, bb) do {                                          \
        g2l16(pt + (it) * 16384,         &Ps[bb][w * 1024]);         \
        g2l16(pt + (it) * 16384 + 8192,  &Ps[bb][w * 1024 + 8192]);  \
        g2l16(vb + (it) * 24576,         &Vs[bb][w * 1024]);         \
        g2l16(vb + (it) * 24576 + 8192,  &Vs[bb][w * 1024 + 8192]);  \
        g2l16(vb + (it) * 24576 + 16384, &Vs[bb][w * 1024 + 16384]); \
    } while (0)

    PSTAGE(0, 0);
    for (int it = 0; it < 12; ++it) {
        const int cur = it & 1;
        LGKM0_BARRIER();                 // all waves done reading buf[cur^1]
        if (it < 11) {
            PSTAGE(it + 1, cur ^ 1);     // 5 loads/wave, stay in flight
            VMCNT_BARRIER(5);            // stage(it) landed everywhere
        } else {
            VMCNT_BARRIER(0);
        }
        #pragma unroll
        for (int c = 0; c < 2; ++c) {
            half8 a[4], bb8[3];
            #pragma unroll
            for (int m = 0; m < 4; ++m) a[m]  = *(const half8*)(&Ps[cur][c * 8192 + offA[m]]);
            #pragma unroll
            for (int n = 0; n < 3; ++n) bb8[n] = *(const half8*)(&Vs[cur][c * 12288 + offB[n]]);
            #pragma unroll
            for (int m = 0; m < 4; ++m)
                #pragma unroll
                for (int n = 0; n < 3; ++n)
                    acc[m][n] = __builtin_amdgcn_mfma_f32_16x16x32_f16(a[m], bb8[n], acc[m][n], 0, 0, 0);
        }
    }
#undef PSTAGE

    const int b = b0 + bz;
    const float* f1b = f1 + ((size_t)b * C_ + ti * 128) * HW_ + tj * 192;
    float*       ob  = out + ((size_t)b * C_ + ti * 128) * HW_ + tj * 192;
    const int col = lane & 15, rbase = (lane >> 4) * 4;
    #pragma unroll
    for (int m = 0; m < 4; ++m)
        #pragma unroll
        for (int n = 0; n < 3; ++n)
            #pragma unroll
            for (int rg = 0; rg < 4; ++rg) {
                int rr = wr + m * 16 + rbase + rg;
                int cc = wc + n * 16 + col;
                ob[(size_t)rr * HW_ + cc] = acc[m][n][rg] + f1b[(size_t)rr * HW_ + cc];
            }
}

// ---------------------------------------------------------------------------
extern "C" void kernel_launch(void* const* d_in, const int* in_sizes, int n_in,
                              void* d_out, int out_size, void* d_ws, size_t ws_size,
                              hipStream_t stream) {
    const float* feat1 = (const float*)d_in[0];
    const float* feat2 = (const float*)d_in[1];
    const float* gamma = (const float*)d_in[2];
    float* out = (float*)d_out;

    const size_t SZ_Q    = (size_t)C_ * HW_ * 2;
    const size_t SZ_ATTN = (size_t)C_ * C_  * 4;
    const size_t SZ_P    = (size_t)C_ * C_  * 2;
    const size_t per_batch = SZ_ATTN + 3 * SZ_Q + SZ_P;

    int nb = (int)(ws_size / per_batch);
    if (nb < 1) nb = 1;
    if (nb > B_) nb = B_;

    char* ws    = (char*)d_ws;
    float* attn = (float*)ws;
    char* q16   = ws + (size_t)nb * SZ_ATTN;
    char* kv16  = q16 + (size_t)nb * SZ_Q;
    char* vtb   = kv16 + (size_t)nb * SZ_Q;
    char* p16   = vtb + (size_t)nb * SZ_Q;

    for (int b0 = 0; b0 < B_; b0 += nb) {
        int cur = (B_ - b0 < nb) ? (B_ - b0) : nb;
        prep_qk<<<cur * 216, 256, 0, stream>>>(feat1, feat2, q16, kv16, b0);
        prep_vt<<<dim3(PV_STEPS, 3, cur), 256, 0, stream>>>(feat2, vtb, b0);
        qk2<<<cur * 36, 512, 0, stream>>>(q16, kv16, attn, cur * 36);
        softmax_p16<<<cur * (C_ / 4), 256, 0, stream>>>(attn, p16, gamma);
        pv2<<<cur * 18, 512, 0, stream>>>(p16, vtb, feat1, out, b0, cur * 18);
    }
}